// Round 1
// baseline (9440.443 us; speedup 1.0000x reference)
//
#include <hip/hip_runtime.h>
#include <math.h>

// GPT forward: L=4, H=12, E=768, HS=64, V=32000, B=2, T=1024
// Inputs (f32 unless noted):
// 0 idx(i32) 1 targets(i32) 2 tok_emb 3 pos_emb 4 Wq 5 bq 6 Wk 7 bk 8 Wv 9 bv
// 10 Wo 11 bo 12 ln1_g 13 ln1_b 14 W1 15 b1 16 W2 17 b2 18 ln2_g 19 ln2_b
// 20 lnf_g 21 lnf_b 22 Wlm 23 blm
// Output: logits [2,1024,32000] f32 then loss scalar at d_out[65536000].

constexpr int Lc = 4, Hc = 12, Ec = 768, HSc = 64, Vc = 32000, Bc = 2, Tc = 1024;
constexpr int BTc = Bc * Tc;               // 2048
constexpr int QKVW = 3 * Ec;               // 2304
constexpr size_t NLOGITS = (size_t)BTc * Vc;  // 65,536,000

// ---------------- repack QKV weights: [L][H][E][HS] -> [L][E][3*768] ----------------
__global__ void repack_wqkv(const float* __restrict__ Wq, const float* __restrict__ Wk,
                            const float* __restrict__ Wv, float* __restrict__ Wp) {
  int i = blockIdx.x * 256 + threadIdx.x;
  if (i >= Lc * Ec * QKVW) return;
  int col = i % QKVW;
  int e = (i / QKVW) % Ec;
  int l = i / (QKVW * Ec);
  const float* src;
  int c = col;
  if (c < Ec) { src = Wq; }
  else if (c < 2 * Ec) { src = Wk; c -= Ec; }
  else { src = Wv; c -= 2 * Ec; }
  int h = c >> 6, hs = c & 63;
  Wp[i] = src[(((size_t)l * Hc + h) * Ec + e) * HSc + hs];
}

__global__ void repack_bqkv(const float* __restrict__ bq, const float* __restrict__ bk,
                            const float* __restrict__ bv, float* __restrict__ bp) {
  int i = blockIdx.x * 256 + threadIdx.x;
  if (i >= Lc * QKVW) return;
  int col = i % QKVW;
  int l = i / QKVW;
  float v;
  if (col < Ec) v = bq[l * Ec + col];
  else if (col < 2 * Ec) v = bk[l * Ec + col - Ec];
  else v = bv[l * Ec + col - 2 * Ec];
  bp[i] = v;
}

// ---------------- embedding ----------------
__global__ void embed_kernel(const int* __restrict__ idx, const float* __restrict__ tok,
                             const float* __restrict__ pos, float* __restrict__ x) {
  int i = blockIdx.x * 256 + threadIdx.x;  // float4 index, total 2048*192
  if (i >= BTc * (Ec / 4)) return;
  int row = i / (Ec / 4);
  int e4 = i % (Ec / 4);
  int t = row & (Tc - 1);
  int token = idx[row];
  float4 a = ((const float4*)(tok + (size_t)token * Ec))[e4];
  float4 b = ((const float4*)(pos + (size_t)t * Ec))[e4];
  float4 o;
  o.x = a.x + b.x; o.y = a.y + b.y; o.z = a.z + b.z; o.w = a.w + b.w;
  ((float4*)(x + (size_t)row * Ec))[e4] = o;
}

// ---------------- layernorm (row = 768) ----------------
__global__ __launch_bounds__(256) void ln_kernel(const float* __restrict__ in,
                                                 const float* __restrict__ g,
                                                 const float* __restrict__ b,
                                                 float* __restrict__ out) {
  int row = blockIdx.x;
  int tid = threadIdx.x;
  const float* xr = in + (size_t)row * Ec;
  float v0 = xr[tid], v1 = xr[tid + 256], v2 = xr[tid + 512];
  float s = v0 + v1 + v2;
  float sq = v0 * v0 + v1 * v1 + v2 * v2;
  __shared__ float rs[256], rq[256];
  rs[tid] = s; rq[tid] = sq;
  __syncthreads();
  for (int off = 128; off > 0; off >>= 1) {
    if (tid < off) { rs[tid] += rs[tid + off]; rq[tid] += rq[tid + off]; }
    __syncthreads();
  }
  float mean = rs[0] * (1.f / Ec);
  float var = rq[0] * (1.f / Ec) - mean * mean;
  float rstd = rsqrtf(var + 1e-5f);
  float* orow = out + (size_t)row * Ec;
  orow[tid]       = (v0 - mean) * rstd * g[tid]       + b[tid];
  orow[tid + 256] = (v1 - mean) * rstd * g[tid + 256] + b[tid + 256];
  orow[tid + 512] = (v2 - mean) * rstd * g[tid + 512] + b[tid + 512];
}

// ---------------- f32 GEMM: C[M,N] = A[M,K] @ B[K,N] + bias (+res) (relu) ----------------
// MODE 0: bias; MODE 1: bias + relu; MODE 2: bias + residual
template <int MODE>
__global__ __launch_bounds__(256) void gemm_f32(const float* __restrict__ A,
                                                const float* __restrict__ B,
                                                const float* __restrict__ bias,
                                                const float* __restrict__ Res,
                                                float* __restrict__ C,
                                                int M, int N, int K) {
  __shared__ float As[16][132];  // transposed A tile: As[k][m]
  __shared__ float Bs[16][132];
  const int tid = threadIdx.x;
  const int n0 = blockIdx.x * 128;
  const int m0 = blockIdx.y * 128;
  const int tx = tid & 15, ty = tid >> 4;

  float acc[8][8];
#pragma unroll
  for (int i = 0; i < 8; i++)
#pragma unroll
    for (int j = 0; j < 8; j++) acc[i][j] = 0.f;

  for (int kt = 0; kt < K; kt += 16) {
#pragma unroll
    for (int it = 0; it < 2; it++) {
      int fidx = it * 256 + tid;
      int ar = fidx >> 2, aq = fidx & 3;
      float4 av = *(const float4*)(A + (size_t)(m0 + ar) * K + kt + aq * 4);
      As[aq * 4 + 0][ar] = av.x;
      As[aq * 4 + 1][ar] = av.y;
      As[aq * 4 + 2][ar] = av.z;
      As[aq * 4 + 3][ar] = av.w;
      int br = fidx >> 5, bq = fidx & 31;
      float4 bv = *(const float4*)(B + (size_t)(kt + br) * N + n0 + bq * 4);
      *(float4*)(&Bs[br][bq * 4]) = bv;
    }
    __syncthreads();
#pragma unroll
    for (int kk = 0; kk < 16; kk++) {
      float a[8], b[8];
      *(float4*)(a + 0) = *(const float4*)(&As[kk][ty * 8]);
      *(float4*)(a + 4) = *(const float4*)(&As[kk][ty * 8 + 4]);
      *(float4*)(b + 0) = *(const float4*)(&Bs[kk][tx * 4]);
      *(float4*)(b + 4) = *(const float4*)(&Bs[kk][64 + tx * 4]);
#pragma unroll
      for (int i = 0; i < 8; i++)
#pragma unroll
        for (int j = 0; j < 8; j++) acc[i][j] = fmaf(a[i], b[j], acc[i][j]);
    }
    __syncthreads();
  }

#pragma unroll
  for (int i = 0; i < 8; i++) {
    int gm = m0 + ty * 8 + i;
#pragma unroll
    for (int c = 0; c < 2; c++) {
      int gn = n0 + c * 64 + tx * 4;
      float4 bv = *(const float4*)(bias + gn);
      float r[4] = {acc[i][c * 4 + 0] + bv.x, acc[i][c * 4 + 1] + bv.y,
                    acc[i][c * 4 + 2] + bv.z, acc[i][c * 4 + 3] + bv.w};
      if (MODE == 2) {
        float4 rv = *(const float4*)(Res + (size_t)gm * N + gn);
        r[0] += rv.x; r[1] += rv.y; r[2] += rv.z; r[3] += rv.w;
      }
      if (MODE == 1) {
#pragma unroll
        for (int j = 0; j < 4; j++) r[j] = fmaxf(r[j], 0.f);
      }
      float4 o; o.x = r[0]; o.y = r[1]; o.z = r[2]; o.w = r[3];
      *(float4*)(C + (size_t)gm * N + gn) = o;
    }
  }
}

// ---------------- flash attention (f32), thread = one query row ----------------
// qkv layout: [BT][2304], q at col h*64, k at 768+h*64, v at 1536+h*64
// out layout: [BT][768] (heads concatenated)
__global__ __launch_bounds__(64) void attn_flash(const float* __restrict__ qkv,
                                                 float* __restrict__ out) {
  __shared__ float Ks[64][68];  // stride 68 floats = 17 float4-banks, coprime w/ 32
  __shared__ float Vs[64][68];
  const int bh = blockIdx.x;  // 0..23
  const int b = bh / Hc, h = bh % Hc;
  const int by = blockIdx.y;  // 0..15
  const int tid = threadIdx.x;
  const int qi = by * 64 + tid;

  const float* qb = qkv + (size_t)(b * Tc + qi) * QKVW + h * 64;
  float q[64], o[64];
#pragma unroll
  for (int i = 0; i < 16; i++) {
    float4 v = ((const float4*)qb)[i];
    q[4 * i + 0] = v.x * 0.125f;
    q[4 * i + 1] = v.y * 0.125f;
    q[4 * i + 2] = v.z * 0.125f;
    q[4 * i + 3] = v.w * 0.125f;
  }
#pragma unroll
  for (int k = 0; k < 64; k++) o[k] = 0.f;
  float m = -1e30f, l = 0.f;

  for (int kt = 0; kt <= by; kt++) {
    __syncthreads();
    const float* kb = qkv + (size_t)(b * Tc + kt * 64 + tid) * QKVW + h * 64 + Ec;
#pragma unroll
    for (int i = 0; i < 16; i++) {
      ((float4*)&Ks[tid][0])[i] = ((const float4*)kb)[i];
      ((float4*)&Vs[tid][0])[i] = ((const float4*)(kb + Ec))[i];
    }
    __syncthreads();
    const int jmax = (kt == by) ? (tid + 1) : 64;
    for (int j = 0; j < jmax; j++) {
      const float4* kr = (const float4*)&Ks[j][0];
      float s = 0.f;
#pragma unroll
      for (int k4 = 0; k4 < 16; k4++) {
        float4 kv = kr[k4];
        s = fmaf(q[4 * k4 + 0], kv.x, s);
        s = fmaf(q[4 * k4 + 1], kv.y, s);
        s = fmaf(q[4 * k4 + 2], kv.z, s);
        s = fmaf(q[4 * k4 + 3], kv.w, s);
      }
      float mn = fmaxf(m, s);
      float alpha = __expf(m - mn);
      float p = __expf(s - mn);
      l = l * alpha + p;
      const float4* vr = (const float4*)&Vs[j][0];
#pragma unroll
      for (int k4 = 0; k4 < 16; k4++) {
        float4 vv = vr[k4];
        o[4 * k4 + 0] = fmaf(o[4 * k4 + 0], alpha, p * vv.x);
        o[4 * k4 + 1] = fmaf(o[4 * k4 + 1], alpha, p * vv.y);
        o[4 * k4 + 2] = fmaf(o[4 * k4 + 2], alpha, p * vv.z);
        o[4 * k4 + 3] = fmaf(o[4 * k4 + 3], alpha, p * vv.w);
      }
      m = mn;
    }
  }
  float inv = 1.f / l;
  float* ob = out + (size_t)(b * Tc + qi) * Ec + h * 64;
#pragma unroll
  for (int i = 0; i < 16; i++) {
    float4 v;
    v.x = o[4 * i + 0] * inv;
    v.y = o[4 * i + 1] * inv;
    v.z = o[4 * i + 2] * inv;
    v.w = o[4 * i + 3] * inv;
    ((float4*)ob)[i] = v;
  }
}

// ---------------- loss ----------------
__global__ void zero_one(float* __restrict__ p) {
  if (blockIdx.x == 0 && threadIdx.x == 0) *p = 0.f;
}

__global__ __launch_bounds__(256) void loss_kernel(const float* __restrict__ logits,
                                                   const int* __restrict__ targets,
                                                   float* __restrict__ loss) {
  int row = blockIdx.x;
  int tid = threadIdx.x;
  const float* lg = logits + (size_t)row * Vc;
  float m = -1e30f;
  for (int v = tid; v < Vc; v += 256) m = fmaxf(m, lg[v]);
  __shared__ float red[256];
  red[tid] = m;
  __syncthreads();
  for (int off = 128; off > 0; off >>= 1) {
    if (tid < off) red[tid] = fmaxf(red[tid], red[tid + off]);
    __syncthreads();
  }
  m = red[0];
  __syncthreads();
  float s = 0.f;
  for (int v = tid; v < Vc; v += 256) s += __expf(lg[v] - m);
  red[tid] = s;
  __syncthreads();
  for (int off = 128; off > 0; off >>= 1) {
    if (tid < off) red[tid] += red[tid + off];
    __syncthreads();
  }
  if (tid == 0) {
    float lse = logf(red[0]) + m;
    float lt = lg[targets[row]];
    atomicAdd(loss, (lse - lt) * (1.0f / BTc));
  }
}

// ---------------- launch ----------------
extern "C" void kernel_launch(void* const* d_in, const int* in_sizes, int n_in,
                              void* d_out, int out_size, void* d_ws, size_t ws_size,
                              hipStream_t stream) {
  const int*   idx     = (const int*)d_in[0];
  const int*   targets = (const int*)d_in[1];
  const float* tok_emb = (const float*)d_in[2];
  const float* pos_emb = (const float*)d_in[3];
  const float* Wq = (const float*)d_in[4];
  const float* bq = (const float*)d_in[5];
  const float* Wk = (const float*)d_in[6];
  const float* bk = (const float*)d_in[7];
  const float* Wv = (const float*)d_in[8];
  const float* bv = (const float*)d_in[9];
  const float* Wo = (const float*)d_in[10];
  const float* bo = (const float*)d_in[11];
  const float* ln1_g = (const float*)d_in[12];
  const float* ln1_b = (const float*)d_in[13];
  const float* W1 = (const float*)d_in[14];
  const float* b1 = (const float*)d_in[15];
  const float* W2 = (const float*)d_in[16];
  const float* b2 = (const float*)d_in[17];
  const float* ln2_g = (const float*)d_in[18];
  const float* ln2_b = (const float*)d_in[19];
  const float* lnf_g = (const float*)d_in[20];
  const float* lnf_b = (const float*)d_in[21];
  const float* Wlm = (const float*)d_in[22];
  const float* blm = (const float*)d_in[23];
  float* out = (float*)d_out;

  float* ws = (float*)d_ws;
  float* x    = ws;                       // 2048*768   = 1,572,864
  float* tmp  = x + (size_t)BTc * Ec;     // 1,572,864
  float* qkv  = tmp + (size_t)BTc * Ec;   // 2048*2304  = 4,718,592
  float* mlph = qkv + (size_t)BTc * QKVW; // 2048*3072  = 6,291,456
  float* wp   = mlph + (size_t)BTc * 4 * Ec;  // 4*768*2304 = 7,077,888
  float* bp   = wp + (size_t)Lc * Ec * QKVW;  // 4*2304

  // repack QKV weights/biases
  repack_wqkv<<<(Lc * Ec * QKVW + 255) / 256, 256, 0, stream>>>(Wq, Wk, Wv, wp);
  repack_bqkv<<<(Lc * QKVW + 255) / 256, 256, 0, stream>>>(bq, bk, bv, bp);

  // embedding
  embed_kernel<<<(BTc * (Ec / 4) + 255) / 256, 256, 0, stream>>>(idx, tok_emb, pos_emb, x);

  for (int l = 0; l < Lc; l++) {
    ln_kernel<<<BTc, 256, 0, stream>>>(x, ln1_g + l * Ec, ln1_b + l * Ec, tmp);
    gemm_f32<0><<<dim3(QKVW / 128, BTc / 128), 256, 0, stream>>>(
        tmp, wp + (size_t)l * Ec * QKVW, bp + l * QKVW, nullptr, qkv, BTc, QKVW, Ec);
    attn_flash<<<dim3(Bc * Hc, Tc / 64), 64, 0, stream>>>(qkv, tmp);
    gemm_f32<2><<<dim3(Ec / 128, BTc / 128), 256, 0, stream>>>(
        tmp, Wo + (size_t)l * Ec * Ec, bo + l * Ec, x, x, BTc, Ec, Ec);
    ln_kernel<<<BTc, 256, 0, stream>>>(x, ln2_g + l * Ec, ln2_b + l * Ec, tmp);
    gemm_f32<1><<<dim3(4 * Ec / 128, BTc / 128), 256, 0, stream>>>(
        tmp, W1 + (size_t)l * Ec * 4 * Ec, b1 + l * 4 * Ec, nullptr, mlph, BTc, 4 * Ec, Ec);
    gemm_f32<2><<<dim3(Ec / 128, BTc / 128), 256, 0, stream>>>(
        mlph, W2 + (size_t)l * 4 * Ec * Ec, b2 + l * Ec, x, x, BTc, Ec, 4 * Ec);
  }

  // final LN + LM head -> logits into d_out
  ln_kernel<<<BTc, 256, 0, stream>>>(x, lnf_g, lnf_b, tmp);
  gemm_f32<0><<<dim3(Vc / 128, BTc / 128), 256, 0, stream>>>(
      tmp, Wlm, blm, nullptr, out, BTc, Vc, Ec);

  // loss
  zero_one<<<1, 64, 0, stream>>>(out + NLOGITS);
  loss_kernel<<<BTc, 256, 0, stream>>>(out, targets, out + NLOGITS);
}